// Round 1
// baseline (95.278 us; speedup 1.0000x reference)
//
#include <hip/hip_runtime.h>

#define C_IN 256
#define HC   128
#define HW   4096
#define TILE_P 64

typedef __attribute__((ext_vector_type(8))) short short8;
typedef __attribute__((ext_vector_type(4))) float f32x4;
typedef __attribute__((ext_vector_type(4))) unsigned short u16x4;

__device__ __forceinline__ unsigned short f2bf(float f) {
    union { float f; unsigned int u; } v; v.f = f;
    return (unsigned short)((v.u + 0x7FFFu + ((v.u >> 16) & 1u)) >> 16);
}

__device__ __forceinline__ float gelu_f(float v) {
    return 0.5f * v * (1.0f + erff(v * 0.70710678118654752440f));
}

__global__ void convert_weights(const float* __restrict__ W1, const float* __restrict__ W2,
                                unsigned short* __restrict__ W1b, unsigned short* __restrict__ W2b) {
    int i = blockIdx.x * blockDim.x + threadIdx.x;
    if (i < HC * C_IN) { W1b[i] = f2bf(W1[i]); W2b[i] = f2bf(W2[i]); }
}

template<bool USE_WS>
__global__ __launch_bounds__(256) void fused_mlp(
    const float* __restrict__ x,
    const float* __restrict__ W1, const float* __restrict__ b1,
    const float* __restrict__ g1, const float* __restrict__ be1,
    const float* __restrict__ W2, const float* __restrict__ b2,
    const float* __restrict__ g2, const float* __restrict__ be2,
    const unsigned short* __restrict__ W1b, const unsigned short* __restrict__ W2b,
    float* __restrict__ out)
{
    __shared__ alignas(16) unsigned short XbfT[TILE_P][264];  // [pixel][k], pad 8
    __shared__ alignas(16) unsigned short HbfT[TILE_P][136];  // [pixel][k], pad 8
    __shared__ float red[4][TILE_P][2];

    const int tid = threadIdx.x;
    const int wv  = tid >> 6;
    const int l   = tid & 63;
    const int l15 = l & 15;
    const int kg  = l >> 4;     // k-group 0..3

    const int tile = blockIdx.x;
    const int b    = tile >> 6;                 // 64 tiles per batch image
    const int p0   = (tile & 63) * TILE_P;
    const float* xb = x   + (size_t)b * (C_IN * HW) + p0;
    float*       ob = out + (size_t)b * (C_IN * HW) + p0;

    // ---- stage X tile: global fp32 -> LDS bf16, transposed [pixel][k] ----
    {
        const int g  = tid & 15;   // pixel group (4 pixels)
        const int cr = tid >> 4;   // row 0..15
        #pragma unroll
        for (int it = 0; it < 16; ++it) {
            const int c = cr + it * 16;
            const f32x4 v = *reinterpret_cast<const f32x4*>(xb + (size_t)c * HW + g * 4);
            XbfT[g*4+0][c] = f2bf(v[0]);
            XbfT[g*4+1][c] = f2bf(v[1]);
            XbfT[g*4+2][c] = f2bf(v[2]);
            XbfT[g*4+3][c] = f2bf(v[3]);
        }
    }
    __syncthreads();

    // ---- GEMM1: H(128x64) = W1(128x256) @ X(256x64) ----
    f32x4 acc1[2][4];
    const f32x4 vzero = {0.f, 0.f, 0.f, 0.f};
    #pragma unroll
    for (int mt = 0; mt < 2; ++mt)
        #pragma unroll
        for (int nt = 0; nt < 4; ++nt) acc1[mt][nt] = vzero;

    const int r0 = wv * 32;
    #pragma unroll
    for (int ks = 0; ks < 8; ++ks) {
        const int kb = ks * 32 + kg * 8;
        short8 a[2], bfr[4];
        #pragma unroll
        for (int mt = 0; mt < 2; ++mt) {
            const int row = r0 + mt*16 + l15;
            if constexpr (USE_WS) {
                a[mt] = *reinterpret_cast<const short8*>(W1b + (size_t)row * C_IN + kb);
            } else {
                const float* wp = W1 + (size_t)row * C_IN + kb;
                const f32x4 f0 = *reinterpret_cast<const f32x4*>(wp);
                const f32x4 f1 = *reinterpret_cast<const f32x4*>(wp + 4);
                #pragma unroll
                for (int e = 0; e < 4; ++e) { a[mt][e] = (short)f2bf(f0[e]); a[mt][4+e] = (short)f2bf(f1[e]); }
            }
        }
        #pragma unroll
        for (int nt = 0; nt < 4; ++nt)
            bfr[nt] = *reinterpret_cast<const short8*>(&XbfT[nt*16 + l15][kb]);
        #pragma unroll
        for (int mt = 0; mt < 2; ++mt)
            #pragma unroll
            for (int nt = 0; nt < 4; ++nt)
                acc1[mt][nt] = __builtin_amdgcn_mfma_f32_16x16x32_bf16(a[mt], bfr[nt], acc1[mt][nt], 0, 0, 0);
    }

    // bias1 + per-column (per-pixel) partial sums for LN1
    #pragma unroll
    for (int mt = 0; mt < 2; ++mt) {
        const f32x4 bias = *reinterpret_cast<const f32x4*>(b1 + r0 + mt*16 + kg*4);
        #pragma unroll
        for (int nt = 0; nt < 4; ++nt) acc1[mt][nt] += bias;
    }
    #pragma unroll
    for (int nt = 0; nt < 4; ++nt) {
        float s = 0.f, q = 0.f;
        #pragma unroll
        for (int mt = 0; mt < 2; ++mt)
            #pragma unroll
            for (int r = 0; r < 4; ++r) { const float v = acc1[mt][nt][r]; s += v; q += v*v; }
        s += __shfl_xor(s, 16); s += __shfl_xor(s, 32);
        q += __shfl_xor(q, 16); q += __shfl_xor(q, 32);
        if (kg == 0) { red[wv][nt*16 + l15][0] = s; red[wv][nt*16 + l15][1] = q; }
    }
    __syncthreads();

    // LN1 apply + gelu -> HbfT (bf16, [pixel][k])
    {
        f32x4 gm[2], bt[2];
        #pragma unroll
        for (int mt = 0; mt < 2; ++mt) {
            gm[mt] = *reinterpret_cast<const f32x4*>(g1  + r0 + mt*16 + kg*4);
            bt[mt] = *reinterpret_cast<const f32x4*>(be1 + r0 + mt*16 + kg*4);
        }
        #pragma unroll
        for (int nt = 0; nt < 4; ++nt) {
            const int col = nt*16 + l15;
            float s = 0.f, q = 0.f;
            #pragma unroll
            for (int w2 = 0; w2 < 4; ++w2) { s += red[w2][col][0]; q += red[w2][col][1]; }
            const float mean = s * (1.0f / HC);
            const float rstd = rsqrtf(q * (1.0f / HC) - mean*mean + 1e-5f);
            #pragma unroll
            for (int mt = 0; mt < 2; ++mt) {
                u16x4 pk;
                #pragma unroll
                for (int r = 0; r < 4; ++r) {
                    float v = (acc1[mt][nt][r] - mean) * rstd;
                    v = v * gm[mt][r] + bt[mt][r];
                    pk[r] = f2bf(gelu_f(v));
                }
                *reinterpret_cast<u16x4*>(&HbfT[col][r0 + mt*16 + kg*4]) = pk;
            }
        }
    }
    __syncthreads();

    // ---- GEMM2: Y(256x64) = W2(256x128) @ H(128x64) ----
    f32x4 acc2[4][4];
    #pragma unroll
    for (int mt = 0; mt < 4; ++mt)
        #pragma unroll
        for (int nt = 0; nt < 4; ++nt) acc2[mt][nt] = vzero;

    const int r2 = wv * 64;
    #pragma unroll
    for (int ks = 0; ks < 4; ++ks) {
        const int kb = ks * 32 + kg * 8;
        short8 a[4], bfr[4];
        #pragma unroll
        for (int mt = 0; mt < 4; ++mt) {
            const int row = r2 + mt*16 + l15;
            if constexpr (USE_WS) {
                a[mt] = *reinterpret_cast<const short8*>(W2b + (size_t)row * HC + kb);
            } else {
                const float* wp = W2 + (size_t)row * HC + kb;
                const f32x4 f0 = *reinterpret_cast<const f32x4*>(wp);
                const f32x4 f1 = *reinterpret_cast<const f32x4*>(wp + 4);
                #pragma unroll
                for (int e = 0; e < 4; ++e) { a[mt][e] = (short)f2bf(f0[e]); a[mt][4+e] = (short)f2bf(f1[e]); }
            }
        }
        #pragma unroll
        for (int nt = 0; nt < 4; ++nt)
            bfr[nt] = *reinterpret_cast<const short8*>(&HbfT[nt*16 + l15][kb]);
        #pragma unroll
        for (int mt = 0; mt < 4; ++mt)
            #pragma unroll
            for (int nt = 0; nt < 4; ++nt)
                acc2[mt][nt] = __builtin_amdgcn_mfma_f32_16x16x32_bf16(a[mt], bfr[nt], acc2[mt][nt], 0, 0, 0);
    }

    // bias2 + LN2 partials
    #pragma unroll
    for (int mt = 0; mt < 4; ++mt) {
        const f32x4 bias = *reinterpret_cast<const f32x4*>(b2 + r2 + mt*16 + kg*4);
        #pragma unroll
        for (int nt = 0; nt < 4; ++nt) acc2[mt][nt] += bias;
    }
    #pragma unroll
    for (int nt = 0; nt < 4; ++nt) {
        float s = 0.f, q = 0.f;
        #pragma unroll
        for (int mt = 0; mt < 4; ++mt)
            #pragma unroll
            for (int r = 0; r < 4; ++r) { const float v = acc2[mt][nt][r]; s += v; q += v*v; }
        s += __shfl_xor(s, 16); s += __shfl_xor(s, 32);
        q += __shfl_xor(q, 16); q += __shfl_xor(q, 32);
        if (kg == 0) { red[wv][nt*16 + l15][0] = s; red[wv][nt*16 + l15][1] = q; }
    }
    __syncthreads();

    // LN2 + residual + gelu -> out
    {
        f32x4 gm[4], bt[4];
        #pragma unroll
        for (int mt = 0; mt < 4; ++mt) {
            gm[mt] = *reinterpret_cast<const f32x4*>(g2  + r2 + mt*16 + kg*4);
            bt[mt] = *reinterpret_cast<const f32x4*>(be2 + r2 + mt*16 + kg*4);
        }
        #pragma unroll
        for (int nt = 0; nt < 4; ++nt) {
            const int col = nt*16 + l15;
            float s = 0.f, q = 0.f;
            #pragma unroll
            for (int w2 = 0; w2 < 4; ++w2) { s += red[w2][col][0]; q += red[w2][col][1]; }
            const float mean = s * (1.0f / C_IN);
            const float rstd = rsqrtf(q * (1.0f / C_IN) - mean*mean + 1e-5f);
            #pragma unroll
            for (int mt = 0; mt < 4; ++mt) {
                #pragma unroll
                for (int r = 0; r < 4; ++r) {
                    const int row = r2 + mt*16 + kg*4 + r;
                    float v = (acc2[mt][nt][r] - mean) * rstd;
                    v = v * gm[mt][r] + bt[mt][r];
                    v += xb[(size_t)row * HW + col];          // residual (L2-hot re-read)
                    ob[(size_t)row * HW + col] = gelu_f(v);
                }
            }
        }
    }
}

extern "C" void kernel_launch(void* const* d_in, const int* in_sizes, int n_in,
                              void* d_out, int out_size, void* d_ws, size_t ws_size,
                              hipStream_t stream) {
    const float* x   = (const float*)d_in[0];
    const float* W1  = (const float*)d_in[1];
    const float* b1  = (const float*)d_in[2];
    const float* g1  = (const float*)d_in[3];
    const float* be1 = (const float*)d_in[4];
    const float* W2  = (const float*)d_in[5];
    const float* b2  = (const float*)d_in[6];
    const float* g2  = (const float*)d_in[7];
    const float* be2 = (const float*)d_in[8];
    float* out = (float*)d_out;

    const size_t need = (size_t)(HC * C_IN + C_IN * HC) * sizeof(unsigned short);
    if (ws_size >= need) {
        unsigned short* W1b = (unsigned short*)d_ws;
        unsigned short* W2b = W1b + HC * C_IN;
        convert_weights<<<128, 256, 0, stream>>>(W1, W2, W1b, W2b);
        fused_mlp<true><<<1024, 256, 0, stream>>>(x, W1, b1, g1, be1, W2, b2, g2, be2, W1b, W2b, out);
    } else {
        fused_mlp<false><<<1024, 256, 0, stream>>>(x, W1, b1, g1, be1, W2, b2, g2, be2, nullptr, nullptr, out);
    }
}

// Round 2
// 58.982 us; speedup vs baseline: 1.6154x; 1.6154x over previous
//
#include <hip/hip_runtime.h>

#define C_IN 256
#define HC   128
#define HW   4096

#define SX 260   // u16 stride, X lds rows ([pixel][k]); 8B-aligned rows, bank-minimal
#define SH 132   // u16 stride, H lds rows ([pixel][k]); 8B-aligned rows
#define SO 68    // f32 stride, out-staging rows; 16B-aligned rows

typedef __attribute__((ext_vector_type(8))) short short8;
typedef __attribute__((ext_vector_type(4))) short short4v;
typedef __attribute__((ext_vector_type(4))) float f32x4;
typedef __attribute__((ext_vector_type(4))) unsigned short u16x4;

__device__ __forceinline__ unsigned short f2bf(float f) {
    union { float f; unsigned int u; } v; v.f = f;
    return (unsigned short)((v.u + 0x7FFFu + ((v.u >> 16) & 1u)) >> 16);
}

// tanh-form GELU: max |err| vs exact-erf gelu ~3e-3, far under threshold.
__device__ __forceinline__ float gelu_f(float v) {
    const float u = v * (0.7978845608028654f + 0.035677408136300125f * v * v);
    const float e = __expf(2.0f * u);
    const float t = 1.0f - 2.0f * __builtin_amdgcn_rcpf(e + 1.0f);
    return 0.5f * v * (1.0f + t);
}

__global__ void convert_weights(const float* __restrict__ W1, const float* __restrict__ W2,
                                unsigned short* __restrict__ W1b, unsigned short* __restrict__ W2b) {
    int i = blockIdx.x * blockDim.x + threadIdx.x;
    if (i < HC * C_IN) { W1b[i] = f2bf(W1[i]); W2b[i] = f2bf(W2[i]); }
}

union SmemU {
    unsigned short Xs[64 * SX];                                   // 33280 B
    struct { unsigned short Hs[64 * SH]; float Ob[4][16][SO]; } u2; // 16896 + 17408
};

template<bool USE_WS>
__global__ __launch_bounds__(256, 4) void fused_mlp(
    const float* __restrict__ x,
    const float* __restrict__ W1, const float* __restrict__ b1,
    const float* __restrict__ g1, const float* __restrict__ be1,
    const float* __restrict__ W2, const float* __restrict__ b2,
    const float* __restrict__ g2, const float* __restrict__ be2,
    const unsigned short* __restrict__ W1b, const unsigned short* __restrict__ W2b,
    float* __restrict__ out)
{
    __shared__ alignas(16) SmemU sm;
    __shared__ float red[4][64][2];

    const int tid = threadIdx.x;
    const int wv  = tid >> 6;
    const int l   = tid & 63;
    const int l15 = l & 15;
    const int kg  = l >> 4;     // 0..3

    const int tile = blockIdx.x;
    const int b    = tile >> 6;
    const int p0   = (tile & 63) * 64;
    const float* xb = x   + (size_t)b * (C_IN * HW) + p0;
    float*       ob = out + (size_t)b * (C_IN * HW) + p0;

    // ---- stage X: fp32 [c][p] -> bf16 LDS [p][c]; 4ch x 4px block per thread ----
    {
        const int g  = l15;      // pixel quad index
        const int cr = kg;       // channel quad within wave
        #pragma unroll
        for (int rnd = 0; rnd < 4; ++rnd) {
            const int c0 = rnd * 64 + wv * 16 + cr * 4;
            f32x4 v[4];
            #pragma unroll
            for (int j = 0; j < 4; ++j)
                v[j] = *reinterpret_cast<const f32x4*>(xb + (size_t)(c0 + j) * HW + g * 4);
            #pragma unroll
            for (int jj = 0; jj < 4; ++jj) {
                u16x4 pk;
                #pragma unroll
                for (int j = 0; j < 4; ++j) pk[j] = f2bf(v[j][jj]);
                *reinterpret_cast<u16x4*>(&sm.Xs[(size_t)(g * 4 + jj) * SX + c0]) = pk;
            }
        }
    }
    __syncthreads();

    // ---- GEMM1: H(128x64) = W1(128x256) @ X(256x64) ----
    f32x4 acc1[2][4];
    const f32x4 vzero = {0.f, 0.f, 0.f, 0.f};
    #pragma unroll
    for (int mt = 0; mt < 2; ++mt)
        #pragma unroll
        for (int nt = 0; nt < 4; ++nt) acc1[mt][nt] = vzero;

    const int r0 = wv * 32;
    #pragma unroll
    for (int ks = 0; ks < 8; ++ks) {
        const int kb = ks * 32 + kg * 8;
        short8 a[2]; short4v blo[4], bhi[4];
        #pragma unroll
        for (int mt = 0; mt < 2; ++mt) {
            const int row = r0 + mt * 16 + l15;
            if constexpr (USE_WS) {
                a[mt] = *reinterpret_cast<const short8*>(W1b + (size_t)row * C_IN + kb);
            } else {
                const float* wp = W1 + (size_t)row * C_IN + kb;
                const f32x4 f0 = *reinterpret_cast<const f32x4*>(wp);
                const f32x4 f1 = *reinterpret_cast<const f32x4*>(wp + 4);
                #pragma unroll
                for (int e = 0; e < 4; ++e) { a[mt][e] = (short)f2bf(f0[e]); a[mt][4+e] = (short)f2bf(f1[e]); }
            }
        }
        #pragma unroll
        for (int nt = 0; nt < 4; ++nt) {
            const unsigned short* p = &sm.Xs[(size_t)(nt * 16 + l15) * SX + kb];
            blo[nt] = *reinterpret_cast<const short4v*>(p);
            bhi[nt] = *reinterpret_cast<const short4v*>(p + 4);
        }
        #pragma unroll
        for (int mt = 0; mt < 2; ++mt)
            #pragma unroll
            for (int nt = 0; nt < 4; ++nt) {
                const short8 bf = __builtin_shufflevector(blo[nt], bhi[nt], 0,1,2,3,4,5,6,7);
                acc1[mt][nt] = __builtin_amdgcn_mfma_f32_16x16x32_bf16(a[mt], bf, acc1[mt][nt], 0, 0, 0);
            }
    }

    // bias1 + LN1 partials (per pixel over 128 channels)
    #pragma unroll
    for (int mt = 0; mt < 2; ++mt) {
        const f32x4 bias = *reinterpret_cast<const f32x4*>(b1 + r0 + mt * 16 + kg * 4);
        #pragma unroll
        for (int nt = 0; nt < 4; ++nt) acc1[mt][nt] += bias;
    }
    #pragma unroll
    for (int nt = 0; nt < 4; ++nt) {
        float s = 0.f, q = 0.f;
        #pragma unroll
        for (int mt = 0; mt < 2; ++mt)
            #pragma unroll
            for (int r = 0; r < 4; ++r) { const float v = acc1[mt][nt][r]; s += v; q += v * v; }
        s += __shfl_xor(s, 16); s += __shfl_xor(s, 32);
        q += __shfl_xor(q, 16); q += __shfl_xor(q, 32);
        if (kg == 0) { red[wv][nt * 16 + l15][0] = s; red[wv][nt * 16 + l15][1] = q; }
    }
    __syncthreads();   // also: X reads done -> Hs (aliasing Xs) may be written

    // LN1 apply + gelu -> Hs (bf16 [pixel][k])
    {
        f32x4 gm[2], bt[2];
        #pragma unroll
        for (int mt = 0; mt < 2; ++mt) {
            gm[mt] = *reinterpret_cast<const f32x4*>(g1  + r0 + mt * 16 + kg * 4);
            bt[mt] = *reinterpret_cast<const f32x4*>(be1 + r0 + mt * 16 + kg * 4);
        }
        #pragma unroll
        for (int nt = 0; nt < 4; ++nt) {
            const int col = nt * 16 + l15;
            float s = 0.f, q = 0.f;
            #pragma unroll
            for (int w2 = 0; w2 < 4; ++w2) { s += red[w2][col][0]; q += red[w2][col][1]; }
            const float mean = s * (1.0f / HC);
            const float rstd = rsqrtf(q * (1.0f / HC) - mean * mean + 1e-5f);
            #pragma unroll
            for (int mt = 0; mt < 2; ++mt) {
                u16x4 pk;
                #pragma unroll
                for (int r = 0; r < 4; ++r) {
                    float v = (acc1[mt][nt][r] - mean) * rstd;
                    v = v * gm[mt][r] + bt[mt][r];
                    pk[r] = f2bf(gelu_f(v));
                }
                *reinterpret_cast<u16x4*>(&sm.u2.Hs[(size_t)col * SH + r0 + mt * 16 + kg * 4]) = pk;
            }
        }
    }
    __syncthreads();

    // ---- GEMM2: Y(256x64) = W2(256x128) @ H(128x64) ----
    f32x4 acc2[4][4];
    #pragma unroll
    for (int mt = 0; mt < 4; ++mt)
        #pragma unroll
        for (int nt = 0; nt < 4; ++nt) acc2[mt][nt] = vzero;

    const int r2 = wv * 64;
    #pragma unroll
    for (int ks = 0; ks < 4; ++ks) {
        const int kb = ks * 32 + kg * 8;
        short8 a[4]; short4v blo[4], bhi[4];
        #pragma unroll
        for (int mt = 0; mt < 4; ++mt) {
            const int row = r2 + mt * 16 + l15;
            if constexpr (USE_WS) {
                a[mt] = *reinterpret_cast<const short8*>(W2b + (size_t)row * HC + kb);
            } else {
                const float* wp = W2 + (size_t)row * HC + kb;
                const f32x4 f0 = *reinterpret_cast<const f32x4*>(wp);
                const f32x4 f1 = *reinterpret_cast<const f32x4*>(wp + 4);
                #pragma unroll
                for (int e = 0; e < 4; ++e) { a[mt][e] = (short)f2bf(f0[e]); a[mt][4+e] = (short)f2bf(f1[e]); }
            }
        }
        #pragma unroll
        for (int nt = 0; nt < 4; ++nt) {
            const unsigned short* p = &sm.u2.Hs[(size_t)(nt * 16 + l15) * SH + kb];
            blo[nt] = *reinterpret_cast<const short4v*>(p);
            bhi[nt] = *reinterpret_cast<const short4v*>(p + 4);
        }
        #pragma unroll
        for (int mt = 0; mt < 4; ++mt)
            #pragma unroll
            for (int nt = 0; nt < 4; ++nt) {
                const short8 bf = __builtin_shufflevector(blo[nt], bhi[nt], 0,1,2,3,4,5,6,7);
                acc2[mt][nt] = __builtin_amdgcn_mfma_f32_16x16x32_bf16(a[mt], bf, acc2[mt][nt], 0, 0, 0);
            }
    }

    // bias2 + LN2 partials (per pixel over 256 channels)
    #pragma unroll
    for (int mt = 0; mt < 4; ++mt) {
        const f32x4 bias = *reinterpret_cast<const f32x4*>(b2 + r2 + mt * 16 + kg * 4);
        #pragma unroll
        for (int nt = 0; nt < 4; ++nt) acc2[mt][nt] += bias;
    }
    #pragma unroll
    for (int nt = 0; nt < 4; ++nt) {
        float s = 0.f, q = 0.f;
        #pragma unroll
        for (int mt = 0; mt < 4; ++mt)
            #pragma unroll
            for (int r = 0; r < 4; ++r) { const float v = acc2[mt][nt][r]; s += v; q += v * v; }
        s += __shfl_xor(s, 16); s += __shfl_xor(s, 32);
        q += __shfl_xor(q, 16); q += __shfl_xor(q, 32);
        if (kg == 0) { red[wv][nt * 16 + l15][0] = s; red[wv][nt * 16 + l15][1] = q; }
    }
    __syncthreads();   // red ready; Hs reads done -> Ob may be written

    // LN2 stats per column (4 columns per lane)
    float mean2[4], rstd2[4];
    #pragma unroll
    for (int nt = 0; nt < 4; ++nt) {
        const int col = nt * 16 + l15;
        float s = 0.f, q = 0.f;
        #pragma unroll
        for (int w2 = 0; w2 < 4; ++w2) { s += red[w2][col][0]; q += red[w2][col][1]; }
        mean2[nt] = s * (1.0f / C_IN);
        rstd2[nt] = rsqrtf(q * (1.0f / C_IN) - mean2[nt] * mean2[nt] + 1e-5f);
    }

    // epilogue: per-wave LDS transpose -> vectorized residual + gelu + 256B-run stores
    #pragma unroll
    for (int mt = 0; mt < 4; ++mt) {
        const f32x4 gm = *reinterpret_cast<const f32x4*>(g2  + r2 + mt * 16 + kg * 4);
        const f32x4 bt = *reinterpret_cast<const f32x4*>(be2 + r2 + mt * 16 + kg * 4);
        #pragma unroll
        for (int nt = 0; nt < 4; ++nt) {
            #pragma unroll
            for (int r = 0; r < 4; ++r) {
                float v = (acc2[mt][nt][r] - mean2[nt]) * rstd2[nt];
                v = v * gm[r] + bt[r];
                sm.u2.Ob[wv][kg * 4 + r][nt * 16 + l15] = v;
            }
        }
        __syncthreads();
        #pragma unroll
        for (int m = 0; m < 4; ++m) {
            const int rl  = kg + 4 * m;
            const int row = r2 + mt * 16 + rl;
            const f32x4 y4 = *reinterpret_cast<const f32x4*>(&sm.u2.Ob[wv][rl][l15 * 4]);
            const f32x4 x4 = *reinterpret_cast<const f32x4*>(xb + (size_t)row * HW + l15 * 4);
            f32x4 o4;
            #pragma unroll
            for (int e = 0; e < 4; ++e) o4[e] = gelu_f(y4[e] + x4[e]);
            *reinterpret_cast<f32x4*>(ob + (size_t)row * HW + l15 * 4) = o4;
        }
        if (mt < 3) __syncthreads();
    }
}

extern "C" void kernel_launch(void* const* d_in, const int* in_sizes, int n_in,
                              void* d_out, int out_size, void* d_ws, size_t ws_size,
                              hipStream_t stream) {
    const float* x   = (const float*)d_in[0];
    const float* W1  = (const float*)d_in[1];
    const float* b1  = (const float*)d_in[2];
    const float* g1  = (const float*)d_in[3];
    const float* be1 = (const float*)d_in[4];
    const float* W2  = (const float*)d_in[5];
    const float* b2  = (const float*)d_in[6];
    const float* g2  = (const float*)d_in[7];
    const float* be2 = (const float*)d_in[8];
    float* out = (float*)d_out;

    const size_t need = (size_t)(HC * C_IN + C_IN * HC) * sizeof(unsigned short);
    if (ws_size >= need) {
        unsigned short* W1b = (unsigned short*)d_ws;
        unsigned short* W2b = W1b + HC * C_IN;
        convert_weights<<<128, 256, 0, stream>>>(W1, W2, W1b, W2b);
        fused_mlp<true><<<1024, 256, 0, stream>>>(x, W1, b1, g1, be1, W2, b2, g2, be2, W1b, W2b, out);
    } else {
        fused_mlp<false><<<1024, 256, 0, stream>>>(x, W1, b1, g1, be1, W2, b2, g2, be2, nullptr, nullptr, out);
    }
}